// Round 1
// baseline (482.217 us; speedup 1.0000x reference)
//
#include <hip/hip_runtime.h>
#include <cstddef>

#define BB   256   // batch
#define UU   8     // in_units
#define ISZ  1152  // in_size
#define JJ   10    // out_units
#define DD   16    // out_size
#define JD   (JJ*DD)        // 160
#define NCH  8              // i-chunks in s kernel (144 i each)
#define ICH  144
#define NCA  36             // i-chunks in agreement kernel (32 i each)
#define ICA  32

// ---------------- transpose: x[b,u,i] -> xT[u,i,b] ----------------
__global__ void transpose_x(const float* __restrict__ x, float* __restrict__ xT) {
    __shared__ float tile[64][65];
    int it = blockIdx.x;          // 18 tiles of 64 i
    int bt = blockIdx.y;          // 4 tiles of 64 b
    int u  = blockIdx.z;          // 8
    int lane = threadIdx.x & 63;
    int w    = threadIdx.x >> 6;  // 0..3
#pragma unroll
    for (int r = 0; r < 16; ++r) {
        int b = bt * 64 + w * 16 + r;
        int i = it * 64 + lane;
        tile[w * 16 + r][lane] = x[(size_t)b * (UU * ISZ) + (size_t)u * ISZ + i];
    }
    __syncthreads();
#pragma unroll
    for (int r = 0; r < 16; ++r) {
        int i = it * 64 + w * 16 + r;
        int b = bt * 64 + lane;
        xT[((size_t)u * ISZ + i) * BB + b] = tile[lane][w * 16 + r];
    }
}

// ---------------- init b_ij = 1 ----------------
__global__ void init_b(float* __restrict__ b_ij) {
    int t = blockIdx.x * 256 + threadIdx.x;
    if (t < ISZ * JJ) b_ij[t] = 1.0f;
}

// ---------------- softmax over i for each j; layout [j][i] ----------------
__global__ void softmax_kernel(const float* __restrict__ b_ij, float* __restrict__ c_ij) {
    int j = blockIdx.x;
    int t = threadIdx.x;
    int lane = t & 63, wv = t >> 6;
    __shared__ float redm[4];
    __shared__ float reds[4];

    float m = -1e30f;
    for (int i = t; i < ISZ; i += 256) m = fmaxf(m, b_ij[j * ISZ + i]);
#pragma unroll
    for (int off = 32; off; off >>= 1) m = fmaxf(m, __shfl_down(m, off, 64));
    if (lane == 0) redm[wv] = m;
    __syncthreads();
    m = fmaxf(fmaxf(redm[0], redm[1]), fmaxf(redm[2], redm[3]));

    float ssum = 0.f;
    for (int i = t; i < ISZ; i += 256) ssum += expf(b_ij[j * ISZ + i] - m);
#pragma unroll
    for (int off = 32; off; off >>= 1) ssum += __shfl_down(ssum, off, 64);
    if (lane == 0) reds[wv] = ssum;
    __syncthreads();
    ssum = reds[0] + reds[1] + reds[2] + reds[3];
    float inv = 1.f / ssum;
    for (int i = t; i < ISZ; i += 256) c_ij[j * ISZ + i] = expf(b_ij[j * ISZ + i] - m) * inv;
}

// ---------------- s partials: s_part[ic][b][j*16+d] ----------------
// grid (NCH, 4, JJ), block 256: lane=b within 64-b tile, wave=group of 4 d's
__global__ __launch_bounds__(256) void s_partial_kernel(
        const float* __restrict__ xT, const float* __restrict__ W,
        const float* __restrict__ c_ij, float* __restrict__ s_part) {
    int ic = blockIdx.x;
    int bt = blockIdx.y;
    int j  = blockIdx.z;
    int lane = threadIdx.x & 63;
    int wv   = threadIdx.x >> 6;
    int b = bt * 64 + lane;
    float acc[4] = {0.f, 0.f, 0.f, 0.f};
    int i0 = ic * ICH;
    for (int ii = 0; ii < ICH; ++ii) {
        int i = i0 + ii;
        float xv[8];
#pragma unroll
        for (int u = 0; u < 8; ++u) xv[u] = xT[((size_t)u * ISZ + i) * BB + b];
        float ci = c_ij[j * ISZ + i];
        const float* Wp = W + (size_t)i * (JJ * DD * UU) + j * (DD * UU) + wv * 4 * UU;
#pragma unroll
        for (int dd = 0; dd < 4; ++dd) {
            float t = 0.f;
#pragma unroll
            for (int u = 0; u < 8; ++u) t += Wp[dd * 8 + u] * xv[u];
            acc[dd] += ci * t;
        }
    }
    int base = (ic * BB + b) * JD + j * DD + wv * 4;
#pragma unroll
    for (int dd = 0; dd < 4; ++dd) s_part[base + dd] = acc[dd];
}

// ---------------- reduce partials + squash; v[b][j*16+d] ----------------
__global__ void reduce_squash_kernel(const float* __restrict__ s_part, float* __restrict__ v) {
    int b = blockIdx.x;
    int t = threadIdx.x;
    __shared__ float sm[JD];
    float s = 0.f;
    if (t < JD) {
#pragma unroll
        for (int ic = 0; ic < NCH; ++ic) s += s_part[(ic * BB + b) * JD + t];
        sm[t] = s;
    }
    __syncthreads();
    if (t < JD) {
        int d = t & 15;
        float msq = 0.f;
#pragma unroll
        for (int j = 0; j < JJ; ++j) { float x = sm[j * DD + d]; msq += x * x; }
        float inv = rsqrtf(msq);
        v[b * JD + t] = msq / (1.f + msq) * s * inv;
    }
}

// ---------------- agreement: b_ij[j][i] += (1/B) sum_{b,d} u_hat * v ----------------
// grid (NCA, JJ), block 256: thread t = batch b
__global__ __launch_bounds__(256) void agreement_kernel(
        const float* __restrict__ xT, const float* __restrict__ W,
        const float* __restrict__ v, float* __restrict__ b_ij) {
    int ic = blockIdx.x;
    int j  = blockIdx.y;
    int t = threadIdx.x;
    int b = t;
    int lane = t & 63, wv = t >> 6;
    float vv[16];
#pragma unroll
    for (int d = 0; d < 16; ++d) vv[d] = v[b * JD + j * DD + d];
    float acc[ICA];
#pragma unroll
    for (int k = 0; k < ICA; ++k) acc[k] = 0.f;
    int i0 = ic * ICA;
    for (int ii = 0; ii < ICA; ++ii) {
        int i = i0 + ii;
        float xv[8];
#pragma unroll
        for (int u = 0; u < 8; ++u) xv[u] = xT[((size_t)u * ISZ + i) * BB + b];
        const float* Wp = W + (size_t)i * (JJ * DD * UU) + j * (DD * UU);
        float sum = 0.f;
#pragma unroll
        for (int d = 0; d < 16; ++d) {
            float tmp = 0.f;
#pragma unroll
            for (int u = 0; u < 8; ++u) tmp += Wp[d * 8 + u] * xv[u];
            sum += tmp * vv[d];
        }
        acc[ii] = sum;
    }
    __shared__ float red[4][ICA];
#pragma unroll
    for (int ii = 0; ii < ICA; ++ii) {
        float a = acc[ii];
#pragma unroll
        for (int off = 32; off; off >>= 1) a += __shfl_down(a, off, 64);
        if (lane == 0) red[wv][ii] = a;
    }
    __syncthreads();
    if (t < ICA) {
        float r = red[0][t] + red[1][t] + red[2][t] + red[3][t];
        b_ij[j * ISZ + i0 + t] += r * (1.0f / (float)BB);
    }
}

extern "C" void kernel_launch(void* const* d_in, const int* in_sizes, int n_in,
                              void* d_out, int out_size, void* d_ws, size_t ws_size,
                              hipStream_t stream) {
    const float* x = (const float*)d_in[0];   // (256, 8, 1152)
    const float* W = (const float*)d_in[1];   // (1, 1152, 10, 16, 8)
    float* out = (float*)d_out;               // (256, 10, 16, 1) -> v

    float* xT     = (float*)d_ws;                  // 8*1152*256 = 2,359,296 floats
    float* b_ij   = xT + (size_t)UU * ISZ * BB;    // 11,520
    float* c_ij   = b_ij + ISZ * JJ;               // 11,520
    float* s_part = c_ij + ISZ * JJ;               // 8*256*160 = 327,680
    float* v      = out;                           // v lives in d_out

    hipLaunchKernelGGL(transpose_x, dim3(18, 4, 8), dim3(256), 0, stream, x, xT);
    hipLaunchKernelGGL(init_b, dim3((ISZ * JJ + 255) / 256), dim3(256), 0, stream, b_ij);

    for (int it = 0; it < 3; ++it) {
        hipLaunchKernelGGL(softmax_kernel, dim3(JJ), dim3(256), 0, stream, b_ij, c_ij);
        hipLaunchKernelGGL(s_partial_kernel, dim3(NCH, 4, JJ), dim3(256), 0, stream,
                           xT, W, c_ij, s_part);
        hipLaunchKernelGGL(reduce_squash_kernel, dim3(BB), dim3(256), 0, stream, s_part, v);
        if (it < 2) {
            hipLaunchKernelGGL(agreement_kernel, dim3(NCA, JJ), dim3(256), 0, stream,
                               xT, W, v, b_ij);
        }
    }
}

// Round 2
// 252.088 us; speedup vs baseline: 1.9129x; 1.9129x over previous
//
#include <hip/hip_runtime.h>
#include <cstddef>

#define BB   256   // batch
#define UU   8     // in_units
#define ISZ  1152  // in_size
#define JJ   10    // out_units
#define DD   16    // out_size
#define JD   (JJ*DD)        // 160
#define DSPL 2              // d halves in s kernel
#define NCA  72             // i-chunks in agreement kernel
#define ICA  16

// ---------------- transpose: x[b,u,i] -> xT[u,i,b] ----------------
__global__ void transpose_x(const float* __restrict__ x, float* __restrict__ xT) {
    __shared__ float tile[64][65];
    int it = blockIdx.x;          // 18 tiles of 64 i
    int bt = blockIdx.y;          // 4 tiles of 64 b
    int u  = blockIdx.z;          // 8
    int lane = threadIdx.x & 63;
    int w    = threadIdx.x >> 6;  // 0..3
#pragma unroll
    for (int r = 0; r < 16; ++r) {
        int b = bt * 64 + w * 16 + r;
        int i = it * 64 + lane;
        tile[w * 16 + r][lane] = x[(size_t)b * (UU * ISZ) + (size_t)u * ISZ + i];
    }
    __syncthreads();
#pragma unroll
    for (int r = 0; r < 16; ++r) {
        int i = it * 64 + w * 16 + r;
        int b = bt * 64 + lane;
        xT[((size_t)u * ISZ + i) * BB + b] = tile[lane][w * 16 + r];
    }
}

// ---------------- init b_ij = 1 ----------------
__global__ void init_b(float* __restrict__ b_ij) {
    int t = blockIdx.x * 256 + threadIdx.x;
    if (t < ISZ * JJ) b_ij[t] = 1.0f;
}

// ---------------- softmax over i for each j; layout [j][i] ----------------
__global__ void softmax_kernel(const float* __restrict__ b_ij, float* __restrict__ c_ij) {
    int j = blockIdx.x;
    int t = threadIdx.x;
    int lane = t & 63, wv = t >> 6;
    __shared__ float redm[4];
    __shared__ float reds[4];

    float m = -1e30f;
    for (int i = t; i < ISZ; i += 256) m = fmaxf(m, b_ij[j * ISZ + i]);
#pragma unroll
    for (int off = 32; off; off >>= 1) m = fmaxf(m, __shfl_down(m, off, 64));
    if (lane == 0) redm[wv] = m;
    __syncthreads();
    m = fmaxf(fmaxf(redm[0], redm[1]), fmaxf(redm[2], redm[3]));

    float ssum = 0.f;
    for (int i = t; i < ISZ; i += 256) ssum += expf(b_ij[j * ISZ + i] - m);
#pragma unroll
    for (int off = 32; off; off >>= 1) ssum += __shfl_down(ssum, off, 64);
    if (lane == 0) reds[wv] = ssum;
    __syncthreads();
    ssum = reds[0] + reds[1] + reds[2] + reds[3];
    float inv = 1.f / ssum;
    for (int i = t; i < ISZ; i += 256) c_ij[j * ISZ + i] = expf(b_ij[j * ISZ + i] - m) * inv;
}

// ---------------- s partials ----------------
// grid (NCH, DSPL, JJ), block 256 = all 256 b. W/c addresses are wave-uniform
// (blockIdx + loop counter only) -> compiler emits s_load (scalar cache).
// s_part layout: [ic][j][dh][b][8] so per-thread 32B stores coalesce per wave.
__global__ __launch_bounds__(256) void s_partial_kernel(
        const float* __restrict__ xT, const float* __restrict__ W,
        const float* __restrict__ c_ij, float* __restrict__ s_part, int ich) {
    int ic = blockIdx.x;
    int dh = blockIdx.y;   // 0..1, 8 d's each
    int j  = blockIdx.z;
    int b  = threadIdx.x;
    float acc[8] = {0.f, 0.f, 0.f, 0.f, 0.f, 0.f, 0.f, 0.f};
    int i0 = ic * ich;
    for (int ii = 0; ii < ich; ++ii) {
        int i = i0 + ii;
        float xv[8];
#pragma unroll
        for (int u = 0; u < 8; ++u) xv[u] = xT[((size_t)u * ISZ + i) * BB + b];
        float ci = c_ij[j * ISZ + i];                       // uniform -> s_load
        const float* Wp = W + (size_t)i * (JJ * DD * UU) + j * (DD * UU) + dh * (8 * UU);
#pragma unroll
        for (int dd = 0; dd < 8; ++dd) {
            float t = 0.f;
#pragma unroll
            for (int u = 0; u < 8; ++u) t += Wp[dd * 8 + u] * xv[u];  // uniform -> s_load
            acc[dd] += ci * t;
        }
    }
    size_t base = ((((size_t)ic * JJ + j) * DSPL + dh) * BB + b) * 8;
#pragma unroll
    for (int dd = 0; dd < 8; ++dd) s_part[base + dd] = acc[dd];
}

// ---------------- reduce partials + squash; v[b][j*16+d] ----------------
__global__ void reduce_squash_kernel(const float* __restrict__ s_part,
                                     float* __restrict__ v, int nch) {
    int b = blockIdx.x;
    int t = threadIdx.x;   // 192 threads, t<160 active
    __shared__ float sm[JD];
    float s = 0.f;
    if (t < JD) {
        int j = t >> 4;
        int d = t & 15;
        int dh = d >> 3, dd = d & 7;
        for (int ic = 0; ic < nch; ++ic)
            s += s_part[((((size_t)ic * JJ + j) * DSPL + dh) * BB + b) * 8 + dd];
        sm[t] = s;
    }
    __syncthreads();
    if (t < JD) {
        int d = t & 15;
        float msq = 0.f;
#pragma unroll
        for (int j = 0; j < JJ; ++j) { float x = sm[j * DD + d]; msq += x * x; }
        float inv = rsqrtf(msq);
        v[b * JD + t] = msq / (1.f + msq) * s * inv;
    }
}

// ---------------- agreement: b_ij[j][i] += (1/B) sum_{b,d} u_hat * v ----------------
// grid (NCA, JJ), block 256 = all b. W scalar loads (uniform); vv[16] per-thread regs.
__global__ __launch_bounds__(256) void agreement_kernel(
        const float* __restrict__ xT, const float* __restrict__ W,
        const float* __restrict__ v, float* __restrict__ b_ij) {
    int ic = blockIdx.x;
    int j  = blockIdx.y;
    int b  = threadIdx.x;
    int lane = b & 63, wv = b >> 6;
    float vv[16];
#pragma unroll
    for (int d = 0; d < 16; ++d) vv[d] = v[b * JD + j * DD + d];
    float acc[ICA];
#pragma unroll
    for (int k = 0; k < ICA; ++k) acc[k] = 0.f;
    int i0 = ic * ICA;
    for (int ii = 0; ii < ICA; ++ii) {
        int i = i0 + ii;
        float xv[8];
#pragma unroll
        for (int u = 0; u < 8; ++u) xv[u] = xT[((size_t)u * ISZ + i) * BB + b];
        const float* Wp = W + (size_t)i * (JJ * DD * UU) + j * (DD * UU);
        float sum = 0.f;
#pragma unroll
        for (int d = 0; d < 16; ++d) {
            float tmp = 0.f;
#pragma unroll
            for (int u = 0; u < 8; ++u) tmp += Wp[d * 8 + u] * xv[u];  // uniform -> s_load
            sum += tmp * vv[d];
        }
        acc[ii] = sum;
    }
    __shared__ float red[4][ICA];
#pragma unroll
    for (int ii = 0; ii < ICA; ++ii) {
        float a = acc[ii];
#pragma unroll
        for (int off = 32; off; off >>= 1) a += __shfl_down(a, off, 64);
        if (lane == 0) red[wv][ii] = a;
    }
    __syncthreads();
    if (b < ICA) {
        float r = red[0][b] + red[1][b] + red[2][b] + red[3][b];
        b_ij[j * ISZ + i0 + b] += r * (1.0f / (float)BB);
    }
}

extern "C" void kernel_launch(void* const* d_in, const int* in_sizes, int n_in,
                              void* d_out, int out_size, void* d_ws, size_t ws_size,
                              hipStream_t stream) {
    const float* x = (const float*)d_in[0];   // (256, 8, 1152)
    const float* W = (const float*)d_in[1];   // (1, 1152, 10, 16, 8)
    float* out = (float*)d_out;               // (256, 10, 16, 1) -> v

    float* xT     = (float*)d_ws;                  // 8*1152*256 = 2,359,296 floats
    float* b_ij   = xT + (size_t)UU * ISZ * BB;    // 11,520
    float* c_ij   = b_ij + ISZ * JJ;               // 11,520
    float* s_part = c_ij + ISZ * JJ;
    float* v      = out;                           // v lives in d_out

    // pick largest i-chunk count whose partial buffer fits ws (ws_size is
    // constant across calls -> same work every call; graph-capture safe)
    size_t avail = ws_size / 4 - ((size_t)UU * ISZ * BB + 2 * ISZ * JJ);
    const int nch_opts[] = {36, 24, 18, 12, 9, 8};
    int nch = 8;
    for (int k = 0; k < 6; ++k) {
        size_t need = (size_t)nch_opts[k] * JJ * DSPL * BB * 8;
        if (need <= avail) { nch = nch_opts[k]; break; }
    }
    int ich = ISZ / nch;

    hipLaunchKernelGGL(transpose_x, dim3(18, 4, 8), dim3(256), 0, stream, x, xT);
    hipLaunchKernelGGL(init_b, dim3((ISZ * JJ + 255) / 256), dim3(256), 0, stream, b_ij);

    for (int it = 0; it < 3; ++it) {
        hipLaunchKernelGGL(softmax_kernel, dim3(JJ), dim3(256), 0, stream, b_ij, c_ij);
        hipLaunchKernelGGL(s_partial_kernel, dim3(nch, DSPL, JJ), dim3(256), 0, stream,
                           xT, W, c_ij, s_part, ich);
        hipLaunchKernelGGL(reduce_squash_kernel, dim3(BB), dim3(192), 0, stream,
                           s_part, v, nch);
        if (it < 2) {
            hipLaunchKernelGGL(agreement_kernel, dim3(NCA, JJ), dim3(256), 0, stream,
                               xT, W, v, b_ij);
        }
    }
}